// Round 1
// baseline (619.832 us; speedup 1.0000x reference)
//
#include <hip/hip_runtime.h>

#define DIM 256
#define T_LEN 4096
#define NBATCH 16
#define K_CODES 1024
#define N_TOK (NBATCH * T_LEN)          // 65536
#define NELEM (NBATCH * DIM * T_LEN)    // 16777216

// d_ws layout (as float):
//   [0, 1024)        cnorm[k] = |e_k|^2
//   [1024, 3072)     per-block loss partials (2048)
//   [4096, 4096+65536) idx[n] as int

#define AI(v, i) ((i) == 0 ? (v).x : (i) == 1 ? (v).y : (i) == 2 ? (v).z : (v).w)

// ---------------- kernel A: code norms ----------------
__global__ __launch_bounds__(256) void knorms(const float* __restrict__ cb,
                                              float* __restrict__ cnorm) {
    int k = blockIdx.x * 4 + (threadIdx.x >> 6);
    int lane = threadIdx.x & 63;
    float4 v = *reinterpret_cast<const float4*>(cb + (size_t)k * DIM + lane * 4);
    float s = v.x * v.x + v.y * v.y + v.z * v.z + v.w * v.w;
    #pragma unroll
    for (int off = 32; off; off >>= 1) s += __shfl_down(s, off);
    if (lane == 0) cnorm[k] = s;
}

// ---------------- kernel B: argmin over codes ----------------
// block: 256 threads, covers 64 consecutive t within one batch b.
// x tile staged in LDS as xs[c][tt]; codebook streamed from L2 (wave-uniform rows).
// per-thread register tile: 4 t (tx) x 8 k (ty), K chunked 128 per pass.
__global__ __launch_bounds__(256) void argmin_kernel(const float* __restrict__ x,
                                                     const float* __restrict__ cb,
                                                     const float* __restrict__ cnorm,
                                                     int* __restrict__ idx) {
    __shared__ float xs[DIM][64];   // 64 KB
    const int tid = threadIdx.x;
    const int n0 = blockIdx.x * 64;
    const int b = n0 >> 12;          // / T_LEN
    const int t0 = n0 & (T_LEN - 1);

    // stage x tile: coalesced (64 contiguous t per instruction)
    {
        const int tt = tid & 63;
        const int cw = tid >> 6;     // wave id 0..3
        const float* xp = x + (size_t)b * DIM * T_LEN + t0 + tt;
        #pragma unroll 8
        for (int j = 0; j < 64; ++j) {
            int c = cw + j * 4;
            xs[c][tt] = xp[(size_t)c * T_LEN];
        }
    }
    __syncthreads();

    const int tx = tid & 15;         // t group
    const int ty = tid >> 4;         // k group
    const int t4 = tx * 4;

    float best[4] = {1e30f, 1e30f, 1e30f, 1e30f};
    int bestk[4] = {0, 0, 0, 0};

    for (int kc = 0; kc < K_CODES; kc += 128) {
        const int kbase = kc + ty * 8;
        float acc[4][8];
        #pragma unroll
        for (int i = 0; i < 4; ++i)
            #pragma unroll
            for (int j = 0; j < 8; ++j) acc[i][j] = 0.0f;

        #pragma unroll 2
        for (int c4 = 0; c4 < DIM; c4 += 4) {
            const float4 a0 = *reinterpret_cast<const float4*>(&xs[c4 + 0][t4]);
            const float4 a1 = *reinterpret_cast<const float4*>(&xs[c4 + 1][t4]);
            const float4 a2 = *reinterpret_cast<const float4*>(&xs[c4 + 2][t4]);
            const float4 a3 = *reinterpret_cast<const float4*>(&xs[c4 + 3][t4]);
            #pragma unroll
            for (int j = 0; j < 8; ++j) {
                const float4 bv =
                    *reinterpret_cast<const float4*>(&cb[(size_t)(kbase + j) * DIM + c4]);
                #pragma unroll
                for (int i = 0; i < 4; ++i) {
                    acc[i][j] = fmaf(AI(a3, i), bv.w,
                                fmaf(AI(a2, i), bv.z,
                                fmaf(AI(a1, i), bv.y,
                                fmaf(AI(a0, i), bv.x, acc[i][j]))));
                }
            }
        }

        #pragma unroll
        for (int j = 0; j < 8; ++j) {
            const int kk = kbase + j;
            const float cn = cnorm[kk];
            #pragma unroll
            for (int i = 0; i < 4; ++i) {
                float s = cn - 2.0f * acc[i][j];
                if (s < best[i]) { best[i] = s; bestk[i] = kk; }
            }
        }
    }

    // cross-thread (ty) reduction per t, reusing xs memory
    __syncthreads();
    float* rb = &xs[0][0];                    // 1024 floats
    int* rk = reinterpret_cast<int*>(&xs[16][0]); // next 1024 slots
    #pragma unroll
    for (int i = 0; i < 4; ++i) {
        rb[ty * 64 + t4 + i] = best[i];
        rk[ty * 64 + t4 + i] = bestk[i];
    }
    __syncthreads();
    if (tid < 64) {
        float bv = rb[tid];
        int bk = rk[tid];
        #pragma unroll
        for (int j = 1; j < 16; ++j) {
            float v = rb[j * 64 + tid];
            int k2 = rk[j * 64 + tid];
            if (v < bv || (v == bv && k2 < bk)) { bv = v; bk = k2; }
        }
        idx[n0 + tid] = bk;
    }
}

// ---------------- kernel C: gather + output + loss partials ----------------
__global__ __launch_bounds__(256) void gather_loss(const float* __restrict__ x,
                                                   const float* __restrict__ cb,
                                                   const int* __restrict__ idx,
                                                   float* __restrict__ out,
                                                   float* __restrict__ part) {
    const int NV4 = NELEM / 4;
    float lsum = 0.0f;
    for (int u = blockIdx.x * 256 + threadIdx.x; u < NV4; u += 2048 * 256) {
        const size_t e0 = (size_t)u * 4;
        const int t = (int)(e0 & (T_LEN - 1));
        const int bc = (int)(e0 >> 12);
        const int c = bc & (DIM - 1);
        const int bb = bc >> 8;
        const int4 id4 = *reinterpret_cast<const int4*>(&idx[bb * T_LEN + t]);
        const float4 xv = *reinterpret_cast<const float4*>(&x[e0]);
        float4 q;
        q.x = cb[(size_t)id4.x * DIM + c];
        q.y = cb[(size_t)id4.y * DIM + c];
        q.z = cb[(size_t)id4.z * DIM + c];
        q.w = cb[(size_t)id4.w * DIM + c];
        *reinterpret_cast<float4*>(&out[e0]) = q;
        const float dx = q.x - xv.x, dy = q.y - xv.y, dz = q.z - xv.z, dw = q.w - xv.w;
        lsum += dx * dx + dy * dy + dz * dz + dw * dw;
    }
    #pragma unroll
    for (int off = 32; off; off >>= 1) lsum += __shfl_down(lsum, off);
    __shared__ float wsum[4];
    const int lane = threadIdx.x & 63, w = threadIdx.x >> 6;
    if (lane == 0) wsum[w] = lsum;
    __syncthreads();
    if (threadIdx.x == 0) part[blockIdx.x] = wsum[0] + wsum[1] + wsum[2] + wsum[3];
}

// ---------------- kernel D: finalize loss ----------------
__global__ __launch_bounds__(256) void finalize(const float* __restrict__ part,
                                                float* __restrict__ loss_out) {
    float s = 0.0f;
    for (int i = threadIdx.x; i < 2048; i += 256) s += part[i];
    #pragma unroll
    for (int off = 32; off; off >>= 1) s += __shfl_down(s, off);
    __shared__ float wsum[4];
    const int lane = threadIdx.x & 63, w = threadIdx.x >> 6;
    if (lane == 0) wsum[w] = s;
    __syncthreads();
    if (threadIdx.x == 0)
        *loss_out = 2.0f * (wsum[0] + wsum[1] + wsum[2] + wsum[3]) / (float)NELEM;
}

extern "C" void kernel_launch(void* const* d_in, const int* in_sizes, int n_in,
                              void* d_out, int out_size, void* d_ws, size_t ws_size,
                              hipStream_t stream) {
    const float* x = (const float*)d_in[0];     // [16,256,4096]
    const float* cb = (const float*)d_in[1];    // [1024,256]
    float* out = (float*)d_out;                 // quant (16777216) + loss (1)
    float* ws = (float*)d_ws;
    float* cnorm = ws;
    float* part = ws + 1024;
    int* idx = (int*)(ws + 4096);

    knorms<<<K_CODES / 4, 256, 0, stream>>>(cb, cnorm);
    argmin_kernel<<<N_TOK / 64, 256, 0, stream>>>(x, cb, cnorm, idx);
    gather_loss<<<2048, 256, 0, stream>>>(x, cb, idx, out, part);
    finalize<<<1, 256, 0, stream>>>(part, out + NELEM);
}

// Round 2
// 135.395 us; speedup vs baseline: 4.5780x; 4.5780x over previous
//
#include <hip/hip_runtime.h>

#define DIM 256
#define T_LEN 4096
#define NBATCH 16
#define K_CODES 1024
#define N_TOK (NBATCH * T_LEN)          // 65536
#define NELEM (NBATCH * DIM * T_LEN)    // 16777216

// d_ws layout (floats):  [0,1024) cnh | [1024,3072) loss partials | [4096, 4096+65536) idx (int)
// d_out[0 .. 131071] (floats) doubles as cb_bf16 scratch (512 KB), overwritten by gather_loss.

typedef __attribute__((ext_vector_type(8))) short bf16x8;     // 8 bf16 = 4 VGPR (guide-verified form)
typedef __attribute__((ext_vector_type(16))) float f32x16;

__device__ __forceinline__ unsigned short f2bf(float f) {     // RNE f32->bf16
    unsigned u = __builtin_bit_cast(unsigned, f);
    return (unsigned short)((u + 0x7FFFu + ((u >> 16) & 1u)) >> 16);
}
__device__ __forceinline__ unsigned f2u(float f) { return __builtin_bit_cast(unsigned, f); }
__device__ __forceinline__ unsigned umin2(unsigned a, unsigned b) { return a < b ? a : b; }

union FragU { bf16x8 v; unsigned short u[8]; };

#define GLLOAD(gsrc, lbase)                                                              \
    __builtin_amdgcn_global_load_lds(                                                    \
        (const __attribute__((address_space(1))) unsigned int*)(gsrc),                   \
        (__attribute__((address_space(3))) unsigned int*)(lbase), 16, 0, 0)

// ---------------- prep: cb f32 -> bf16, cnh[k] = 2 + 0.5*|e_k|^2 ----------------
__global__ __launch_bounds__(256) void prep(const float* __restrict__ cb,
                                            unsigned short* __restrict__ cbb,
                                            float* __restrict__ cnh) {
    int k = blockIdx.x * 4 + (threadIdx.x >> 6);
    int lane = threadIdx.x & 63;
    float4 v = *reinterpret_cast<const float4*>(cb + (size_t)k * DIM + lane * 4);
    float s = v.x * v.x + v.y * v.y + v.z * v.z + v.w * v.w;
    #pragma unroll
    for (int off = 32; off; off >>= 1) s += __shfl_down(s, off);
    if (lane == 0) cnh[k] = 2.0f + 0.5f * s;
    ushort4 o;
    o.x = f2bf(v.x); o.y = f2bf(v.y); o.z = f2bf(v.z); o.w = f2bf(v.w);
    *reinterpret_cast<ushort4*>(cbb + (size_t)k * DIM + lane * 4) = o;
}

// ---------------- argmin via MFMA ----------------
// 256 blocks x 256 thr (4 waves). Wave owns 64 tokens (2 col-groups of 32).
// x fragments in registers; codebook swept through double-buffered 32KB LDS chunks.
__global__ __launch_bounds__(256, 1) void argmin_mfma(const float* __restrict__ x,
                                                      const unsigned short* __restrict__ cbb,
                                                      const float* __restrict__ cnh,
                                                      int* __restrict__ idx) {
    __shared__ __align__(16) unsigned short cbuf[2][64 * 256];  // 2 x 32 KB
    const int tid = threadIdx.x;
    const int w = tid >> 6, lane = tid & 63, hi = lane >> 5, ln31 = lane & 31;
    const int tw = blockIdx.x * 256 + w * 64;
    const int b = tw >> 12, t0 = tw & (T_LEN - 1);

    // ---- load x fragments: B-layout, elem i -> token t0+grp*32+ln31, c = cf*16 + hi*8 + i ----
    FragU xf[2][16];
    #pragma unroll
    for (int grp = 0; grp < 2; ++grp) {
        const float* xb = x + (size_t)b * DIM * T_LEN + (t0 + grp * 32 + ln31);
        #pragma unroll
        for (int cf = 0; cf < 16; ++cf) {
            #pragma unroll
            for (int i = 0; i < 8; ++i) {
                int c = cf * 16 + hi * 8 + i;
                xf[grp][cf].u[i] = f2bf(xb[(size_t)c * T_LEN]);
            }
        }
    }

    // ---- chunk staging: linear LDS dest, pre-swizzled global source (involution) ----
    auto stage = [&](int kc, int buf) {
        const char* gc = (const char*)cbb + kc * 32768;
        char* lb = (char*)&cbuf[buf][0];
        #pragma unroll
        for (int j = 0; j < 8; ++j) {
            int o = j * 4096 + w * 1024 + lane * 16;
            int so = o ^ (((o >> 9) & 7) << 4);
            GLLOAD(gc + so, lb + j * 4096 + w * 1024);   // lds base wave-uniform; HW adds lane*16
        }
    };

    stage(0, 0);
    unsigned best0 = 0xFFFFFFFFu, best1 = 0xFFFFFFFFu;

    for (int kc = 0; kc < 16; ++kc) {
        const int cur = kc & 1;
        if (kc < 15) {
            stage(kc + 1, cur ^ 1);
            asm volatile("s_waitcnt vmcnt(8)" ::: "memory");   // chunk kc landed; prefetch in flight
        } else {
            asm volatile("s_waitcnt vmcnt(0)" ::: "memory");
        }
        __syncthreads();

        const char* cbp = (const char*)&cbuf[cur][0];
        #pragma unroll
        for (int ct = 0; ct < 2; ++ct) {
            const int r = ct * 32 + ln31;                       // code row this lane supplies
            bf16x8 af[16];
            #pragma unroll
            for (int cf = 0; cf < 16; ++cf) {                   // swizzled ds_read_b128
                int cbyte = cf * 32 + hi * 16;
                af[cf] = *(const bf16x8*)(cbp + r * 512 + (cbyte ^ ((r & 7) << 4)));
            }
            f32x16 acc0, acc1;
            #pragma unroll
            for (int i = 0; i < 16; ++i) { acc0[i] = 0.0f; acc1[i] = 0.0f; }
            #pragma unroll
            for (int cf = 0; cf < 16; ++cf) {
                acc0 = __builtin_amdgcn_mfma_f32_32x32x16_bf16(af[cf], xf[0][cf].v, acc0, 0, 0, 0);
                acc1 = __builtin_amdgcn_mfma_f32_32x32x16_bf16(af[cf], xf[1][cf].v, acc1, 0, 0, 0);
            }
            const int kbl = kc * 64 + ct * 32 + hi * 4;         // + (reg&3) + 8*(reg>>2) = code
            #pragma unroll
            for (int rg = 0; rg < 16; ++rg) {
                const int kk = kbl + (rg & 3) + 8 * (rg >> 2);
                const float cn = cnh[kk];
                // score = 2 + cn/2 - dot  in [1.7, 2.3] -> positive-float bit ordering valid
                best0 = umin2(best0, (f2u(cn - acc0[rg]) & 0xFFFFFC00u) | (unsigned)kk);
                best1 = umin2(best1, (f2u(cn - acc1[rg]) & 0xFFFFFC00u) | (unsigned)kk);
            }
        }
        __syncthreads();   // all waves done with buf[cur] before it is re-staged
    }

    // lanes l and l^32 hold the two halves of token col (lane&31)
    best0 = umin2(best0, __shfl_xor(best0, 32));
    best1 = umin2(best1, __shfl_xor(best1, 32));
    unsigned bk = (lane < 32) ? best0 : best1;
    idx[tw + lane] = (int)(bk & 1023u);
}

// ---------------- gather + output + loss partials (round-1 proven) ----------------
__global__ __launch_bounds__(256) void gather_loss(const float* __restrict__ x,
                                                   const float* __restrict__ cb,
                                                   const int* __restrict__ idx,
                                                   float* __restrict__ out,
                                                   float* __restrict__ part) {
    const int NV4 = NELEM / 4;
    float lsum = 0.0f;
    for (int u = blockIdx.x * 256 + threadIdx.x; u < NV4; u += 2048 * 256) {
        const size_t e0 = (size_t)u * 4;
        const int t = (int)(e0 & (T_LEN - 1));
        const int bc = (int)(e0 >> 12);
        const int c = bc & (DIM - 1);
        const int bb = bc >> 8;
        const int4 id4 = *reinterpret_cast<const int4*>(&idx[bb * T_LEN + t]);
        const float4 xv = *reinterpret_cast<const float4*>(&x[e0]);
        float4 q;
        q.x = cb[(size_t)id4.x * DIM + c];
        q.y = cb[(size_t)id4.y * DIM + c];
        q.z = cb[(size_t)id4.z * DIM + c];
        q.w = cb[(size_t)id4.w * DIM + c];
        *reinterpret_cast<float4*>(&out[e0]) = q;
        const float dx = q.x - xv.x, dy = q.y - xv.y, dz = q.z - xv.z, dw = q.w - xv.w;
        lsum += dx * dx + dy * dy + dz * dz + dw * dw;
    }
    #pragma unroll
    for (int off = 32; off; off >>= 1) lsum += __shfl_down(lsum, off);
    __shared__ float wsum[4];
    const int lane = threadIdx.x & 63, wv = threadIdx.x >> 6;
    if (lane == 0) wsum[wv] = lsum;
    __syncthreads();
    if (threadIdx.x == 0) part[blockIdx.x] = wsum[0] + wsum[1] + wsum[2] + wsum[3];
}

__global__ __launch_bounds__(256) void finalize(const float* __restrict__ part,
                                                float* __restrict__ loss_out) {
    float s = 0.0f;
    for (int i = threadIdx.x; i < 2048; i += 256) s += part[i];
    #pragma unroll
    for (int off = 32; off; off >>= 1) s += __shfl_down(s, off);
    __shared__ float wsum[4];
    const int lane = threadIdx.x & 63, wv = threadIdx.x >> 6;
    if (lane == 0) wsum[wv] = s;
    __syncthreads();
    if (threadIdx.x == 0)
        *loss_out = 2.0f * (wsum[0] + wsum[1] + wsum[2] + wsum[3]) / (float)NELEM;
}

extern "C" void kernel_launch(void* const* d_in, const int* in_sizes, int n_in,
                              void* d_out, int out_size, void* d_ws, size_t ws_size,
                              hipStream_t stream) {
    const float* x  = (const float*)d_in[0];    // [16,256,4096]
    const float* cb = (const float*)d_in[1];    // [1024,256]
    float* out = (float*)d_out;                 // quant (16777216) + loss (1)
    float* ws  = (float*)d_ws;
    float* cnh  = ws;                           // 1024 f
    float* part = ws + 1024;                    // 2048 f
    int*   idx  = (int*)(ws + 4096);            // 65536 i
    unsigned short* cbb = (unsigned short*)out; // 512 KB scratch, overwritten by gather_loss

    prep<<<K_CODES / 4, 256, 0, stream>>>(cb, cbb, cnh);
    argmin_mfma<<<N_TOK / 256, 256, 0, stream>>>(x, cbb, cnh, idx);
    gather_loss<<<2048, 256, 0, stream>>>(x, cb, idx, out, part);
    finalize<<<1, 256, 0, stream>>>(part, out + NELEM);
}

// Round 3
// 110.359 us; speedup vs baseline: 5.6165x; 1.2269x over previous
//
#include <hip/hip_runtime.h>

#define DIM 256
#define T_LEN 4096
#define NBATCH 16
#define K_CODES 1024
#define N_TOK (NBATCH * T_LEN)          // 65536
#define NELEM (NBATCH * DIM * T_LEN)    // 16777216

// d_ws layout (floats):  [0,1024) cnh | [1024,1536) loss partials (512) | [4096, 4096+65536) idx (int)
// d_out[0 .. 131071] (floats) doubles as cb_bf16 scratch (512 KB): written by prep, read by
// argmin_mfma, dead by the time scatter overwrites d_out.

typedef __attribute__((ext_vector_type(8))) short bf16x8;     // 8 bf16 = 4 VGPR
typedef __attribute__((ext_vector_type(16))) float f32x16;

__device__ __forceinline__ unsigned short f2bf(float f) {     // RNE f32->bf16
    unsigned u = __builtin_bit_cast(unsigned, f);
    return (unsigned short)((u + 0x7FFFu + ((u >> 16) & 1u)) >> 16);
}
__device__ __forceinline__ unsigned f2u(float f) { return __builtin_bit_cast(unsigned, f); }
__device__ __forceinline__ float u2f(unsigned u) { return __builtin_bit_cast(float, u); }
__device__ __forceinline__ unsigned umin2(unsigned a, unsigned b) { return a < b ? a : b; }

union FragU { bf16x8 v; unsigned short u[8]; };

#define GLLOAD(gsrc, lbase)                                                              \
    __builtin_amdgcn_global_load_lds(                                                    \
        (const __attribute__((address_space(1))) unsigned int*)(gsrc),                   \
        (__attribute__((address_space(3))) unsigned int*)(lbase), 16, 0, 0)

// ---------------- prep: cb f32 -> bf16, cnh[k] = 2 + 0.5*|e_k|^2 ----------------
__global__ __launch_bounds__(256) void prep(const float* __restrict__ cb,
                                            unsigned short* __restrict__ cbb,
                                            float* __restrict__ cnh) {
    int k = blockIdx.x * 4 + (threadIdx.x >> 6);
    int lane = threadIdx.x & 63;
    float4 v = *reinterpret_cast<const float4*>(cb + (size_t)k * DIM + lane * 4);
    float s = v.x * v.x + v.y * v.y + v.z * v.z + v.w * v.w;
    #pragma unroll
    for (int off = 32; off; off >>= 1) s += __shfl_down(s, off);
    if (lane == 0) cnh[k] = 2.0f + 0.5f * s;
    ushort4 o;
    o.x = f2bf(v.x); o.y = f2bf(v.y); o.z = f2bf(v.z); o.w = f2bf(v.w);
    *reinterpret_cast<ushort4*>(cbb + (size_t)k * DIM + lane * 4) = o;
}

// ---------------- argmin via MFMA + fused loss partials ----------------
// 512 blocks x 4 waves, 32 tokens/wave (128/block) -> 2 blocks/CU, 2 waves/SIMD.
__global__ __launch_bounds__(256, 2) void argmin_mfma(const float* __restrict__ x,
                                                      const unsigned short* __restrict__ cbb,
                                                      const float* __restrict__ cnh,
                                                      int* __restrict__ idx,
                                                      float* __restrict__ part) {
    __shared__ __align__(16) unsigned short cbuf[2][64 * 256];  // 2 x 32 KB
    __shared__ float wpart[4];
    const int tid = threadIdx.x;
    const int w = tid >> 6, lane = tid & 63, hi = lane >> 5, ln31 = lane & 31;
    const int tw = blockIdx.x * 128 + w * 32;     // first token of this wave
    const int b = tw >> 12, t0 = tw & (T_LEN - 1);

    // ---- x fragments (B-operand): lane pair (ln31, hi) -> token t0+ln31, c = cf*16 + hi*8 + i.
    // Also accumulate exact fp32 |x|^2 partial per thread.
    FragU xf[16];
    float x2 = 0.0f;
    {
        const float* xb = x + (size_t)b * DIM * T_LEN + (t0 + ln31);
        #pragma unroll
        for (int cf = 0; cf < 16; ++cf) {
            #pragma unroll
            for (int i = 0; i < 8; ++i) {
                int c = cf * 16 + hi * 8 + i;
                float xv = xb[(size_t)c * T_LEN];
                x2 += xv * xv;
                xf[cf].u[i] = f2bf(xv);
            }
        }
    }

    // ---- chunk staging: linear LDS dest, pre-swizzled global source (5-bit involution) ----
    auto stage = [&](int kc, int buf) {
        const char* gc = (const char*)cbb + kc * 32768;
        char* lb = (char*)&cbuf[buf][0];
        #pragma unroll
        for (int j = 0; j < 8; ++j) {
            int o = j * 4096 + w * 1024 + lane * 16;
            int so = o ^ (((o >> 9) & 31) << 4);
            GLLOAD(gc + so, lb + j * 4096 + w * 1024);
        }
    };

    stage(0, 0);
    unsigned best = 0xFFFFFFFFu;

    for (int kc = 0; kc < 16; ++kc) {
        const int cur = kc & 1;
        if (kc < 15) {
            stage(kc + 1, cur ^ 1);
            asm volatile("s_waitcnt vmcnt(8)" ::: "memory");
        } else {
            asm volatile("s_waitcnt vmcnt(0)" ::: "memory");
        }
        __syncthreads();

        const char* cbp = (const char*)&cbuf[cur][0];
        #pragma unroll
        for (int ct = 0; ct < 2; ++ct) {
            const int r = ct * 32 + ln31;                       // code row this lane supplies
            bf16x8 af[16];
            #pragma unroll
            for (int cf = 0; cf < 16; ++cf) {                   // swizzled ds_read_b128
                int cbyte = cf * 32 + hi * 16;
                af[cf] = *(const bf16x8*)(cbp + r * 512 + (cbyte ^ ((r & 31) << 4)));
            }
            f32x16 accA, accB;
            #pragma unroll
            for (int i = 0; i < 16; ++i) { accA[i] = 0.0f; accB[i] = 0.0f; }
            __builtin_amdgcn_s_setprio(1);
            #pragma unroll
            for (int cf = 0; cf < 8; ++cf) {                    // two 8-deep chains (ILP)
                accA = __builtin_amdgcn_mfma_f32_32x32x16_bf16(af[cf], xf[cf].v, accA, 0, 0, 0);
                accB = __builtin_amdgcn_mfma_f32_32x32x16_bf16(af[cf + 8], xf[cf + 8].v, accB, 0, 0, 0);
            }
            __builtin_amdgcn_s_setprio(0);
            const int kbl = kc * 64 + ct * 32 + hi * 4;
            #pragma unroll
            for (int rg = 0; rg < 16; ++rg) {
                const int kk = kbl + (rg & 3) + 8 * (rg >> 2);
                const float cn = cnh[kk];                        // wave-uniform -> s_load
                float s = cn - (accA[rg] + accB[rg]);            // s in [1.7,2.3] > 0
                best = umin2(best, (f2u(s) & 0xFFFFFC00u) | (unsigned)kk);
            }
        }
        __syncthreads();
    }

    // merge hi halves: lanes l, l^32 hold disjoint code sets & disjoint channel halves
    best = umin2(best, __shfl_xor(best, 32));
    float x2tok = x2 + __shfl_xor(x2, 32);                       // |x_t|^2, t = tw + ln31
    if (lane < 32) idx[tw + ln31] = (int)(best & 1023u);

    // per-token loss contribution: |e|^2 - 2 dot + |x|^2 = 2*(s-2) + |x|^2
    float contrib = 2.0f * (u2f(best & 0xFFFFFC00u) - 2.0f) + x2tok;
    #pragma unroll
    for (int off = 16; off; off >>= 1) contrib += __shfl_xor(contrib, off);
    if (lane == 0) wpart[w] = contrib;                           // lanes 32-63 hold a dup copy
    __syncthreads();
    if (tid == 0) part[blockIdx.x] = wpart[0] + wpart[1] + wpart[2] + wpart[3];
}

// ---------------- scatter: gather fp32 cb rows -> LDS transpose -> coalesced out ----------------
// 2048 blocks x 256 thr, 32 tokens/block. ~37 KB LDS -> 4 blocks/CU.
__global__ __launch_bounds__(256) void scatter(const float* __restrict__ cb,
                                               const int* __restrict__ idx,
                                               float* __restrict__ out) {
    __shared__ float xs[DIM][36];    // pad 36: phase-1 writes conflict-free, float2-aligned reads
    __shared__ int kk[32];
    const int tid = threadIdx.x;
    const int n0 = blockIdx.x * 32;
    const int b = n0 >> 12, t0 = n0 & (T_LEN - 1);

    if (tid < 32) kk[tid] = idx[n0 + tid];
    __syncthreads();

    {   // phase 1: coalesced row gather (float4), transpose into LDS
        const int w = tid >> 6, l = tid & 63, tt = l & 31, q0 = l >> 5;
        const float* row = cb + (size_t)kk[tt] * DIM;
        #pragma unroll
        for (int r = 0; r < 8; ++r) {
            const int q = r * 8 + w * 2 + q0;                    // quad 0..63
            const float4 v = *reinterpret_cast<const float4*>(row + q * 4);
            xs[q * 4 + 0][tt] = v.x;
            xs[q * 4 + 1][tt] = v.y;
            xs[q * 4 + 2][tt] = v.z;
            xs[q * 4 + 3][tt] = v.w;
        }
    }
    __syncthreads();

    {   // phase 2: coalesced float2 writes over t
        const int c16 = tid >> 4, th = tid & 15;
        #pragma unroll
        for (int r = 0; r < 16; ++r) {
            const int c = r * 16 + c16;
            const float2 v = *reinterpret_cast<const float2*>(&xs[c][2 * th]);
            *reinterpret_cast<float2*>(&out[(((size_t)b * DIM + c) << 12) + t0 + 2 * th]) = v;
        }
    }
}

// ---------------- finalize loss ----------------
__global__ __launch_bounds__(256) void finalize(const float* __restrict__ part,
                                                float* __restrict__ loss_out) {
    double s = 0.0;
    for (int i = threadIdx.x; i < 512; i += 256) s += (double)part[i];
    #pragma unroll
    for (int off = 32; off; off >>= 1) s += __shfl_down(s, off);
    __shared__ double wsum[4];
    const int lane = threadIdx.x & 63, wv = threadIdx.x >> 6;
    if (lane == 0) wsum[wv] = s;
    __syncthreads();
    if (threadIdx.x == 0)
        *loss_out = (float)(2.0 * (wsum[0] + wsum[1] + wsum[2] + wsum[3]) / (double)NELEM);
}

extern "C" void kernel_launch(void* const* d_in, const int* in_sizes, int n_in,
                              void* d_out, int out_size, void* d_ws, size_t ws_size,
                              hipStream_t stream) {
    const float* x  = (const float*)d_in[0];    // [16,256,4096]
    const float* cb = (const float*)d_in[1];    // [1024,256]
    float* out = (float*)d_out;                 // quant (16777216) + loss (1)
    float* ws  = (float*)d_ws;
    float* cnh  = ws;                           // 1024 f
    float* part = ws + 1024;                    // 512 f
    int*   idx  = (int*)(ws + 4096);            // 65536 i
    unsigned short* cbb = (unsigned short*)out; // 512 KB scratch; dead before scatter runs

    prep<<<K_CODES / 4, 256, 0, stream>>>(cb, cbb, cnh);
    argmin_mfma<<<N_TOK / 128, 256, 0, stream>>>(x, cbb, cnh, idx, part);
    scatter<<<N_TOK / 32, 256, 0, stream>>>(cb, idx, out);
    finalize<<<1, 256, 0, stream>>>(part, out + NELEM);
}